// Round 2
// baseline (115.829 us; speedup 1.0000x reference)
//
#include <hip/hip_runtime.h>

// GATLayer reduces to out = x @ W^T:
//   out = einsum('bnjh,bnhd->bnhd', alpha, h); j appears only in alpha and
//   softmax over j sums to 1 (self-edge guarantees a finite row)
//   => out = h = x @ W^T for ANY adj / a_w (both numerically dead).
// B=4, N=2048, IN=256, OUT=256.
//
// Error-compensated bf16 MFMA (Ootomo split), scale-robust ~2^-17 rel err:
//   acc += Wh*Xh + Wl*Xh + Wh*Xl   (A-operand = W, B-operand = X)
//
// Kernel 1 (split_w): W fp32 -> Wh/Wl bf16 in d_ws ONCE (removes the
//   per-block re-conversion VALU chains that throttled the previous version).
// Kernel 2 (gat_gemm): 1024 blocks x 256 thr; block = 16 rows x 128 cols
//   (4 blocks/CU -> 4 waves/SIMD for L2 latency hiding). X staged fp32->
//   bf16(hi,lo) in LDS; W fragments load as short8 directly from L2.
// Operand swap puts out-cols in the reg dim of D -> float4 epilogue stores.

typedef __attribute__((ext_vector_type(8))) short short8;
typedef __attribute__((ext_vector_type(4))) float floatx4;

__device__ inline int cvtpk_bf16(float a, float b) {
    // dst.lo16 = bf16(a), dst.hi16 = bf16(b), RNE
    int r;
    asm("v_cvt_pk_bf16_f32 %0, %1, %2" : "=v"(r) : "v"(a), "v"(b));
    return r;
}
__device__ inline float lo_bf2f(int p) { return __uint_as_float((unsigned)p << 16); }
__device__ inline float hi_bf2f(int p) { return __uint_as_float((unsigned)p & 0xffff0000u); }

// ---- Kernel 1: split W[256][256] fp32 -> Wh, Wl bf16 (row-major) ----
__global__ __launch_bounds__(256) void split_w(const float* __restrict__ W,
                                               short* __restrict__ Wh,
                                               short* __restrict__ Wl) {
    int gid = blockIdx.x * 256 + threadIdx.x;       // 16384 float4s
    float4 v = ((const float4*)W)[gid];
    int h0 = cvtpk_bf16(v.x, v.y);
    int h1 = cvtpk_bf16(v.z, v.w);
    int l0 = cvtpk_bf16(v.x - lo_bf2f(h0), v.y - hi_bf2f(h0));
    int l1 = cvtpk_bf16(v.z - lo_bf2f(h1), v.w - hi_bf2f(h1));
    *(int2*)(Wh + (size_t)gid * 4) = make_int2(h0, h1);
    *(int2*)(Wl + (size_t)gid * 4) = make_int2(l0, l1);
}

#define LSTR 264  // 256 + 8 shorts: 16B-aligned rows, worst aliasing 2-way (free)

// ---- Kernel 2: out[8192][256] = X[8192][256] @ W^T ----
__global__ __launch_bounds__(256) void gat_gemm(const float* __restrict__ X,
                                                const short* __restrict__ Wh,
                                                const short* __restrict__ Wl,
                                                float* __restrict__ out) {
    __shared__ short xh[16 * LSTR];
    __shared__ short xl[16 * LSTR];

    const int rb = blockIdx.x >> 1;   // row-tile (0..511)
    const int cb = blockIdx.x & 1;    // col half (0..1)
    const int r0 = rb * 16;
    const int t  = threadIdx.x;

    // Stage 16 rows x 256 f (fp32 -> bf16 hi+lo). 1024 float4 loads, 4/thread.
    const float4* X4 = (const float4*)(X + (size_t)r0 * 256);
    #pragma unroll
    for (int k = 0; k < 4; ++k) {
        int idx = t + 256 * k;          // 0..1023
        int row = idx >> 6;             // 64 float4 per row
        int c4  = idx & 63;
        float4 v = X4[idx];
        int h0 = cvtpk_bf16(v.x, v.y);
        int h1 = cvtpk_bf16(v.z, v.w);
        int l0 = cvtpk_bf16(v.x - lo_bf2f(h0), v.y - hi_bf2f(h0));
        int l1 = cvtpk_bf16(v.z - lo_bf2f(h1), v.w - hi_bf2f(h1));
        *(int2*)&xh[row * LSTR + c4 * 4] = make_int2(h0, h1);
        *(int2*)&xl[row * LSTR + c4 * 4] = make_int2(l0, l1);
    }
    __syncthreads();

    const int lane = t & 63;
    const int wave = t >> 6;            // 4 waves; wave w -> 32-col slice
    const int q    = lane >> 4;         // k-group (0..3)
    const int m    = lane & 15;         // A-row (W row) / B-col (x row) index
    const int o0   = cb * 128 + wave * 32;

    floatx4 acc[2] = {};                // 2 col-tiles of 16

    #pragma unroll
    for (int it = 0; it < 8; ++it) {
        const int f0 = it * 32 + q * 8;
        // B operand (x): lane m holds x row r0+m, k = f0..f0+7
        short8 bxh = *(const short8*)&xh[m * LSTR + f0];
        short8 bxl = *(const short8*)&xl[m * LSTR + f0];
        #pragma unroll
        for (int nt = 0; nt < 2; ++nt) {
            // A operand (W): lane m holds W row o0+nt*16+m, k = f0..f0+7
            const size_t wo = (size_t)(o0 + nt * 16 + m) * 256 + f0;
            short8 wh8 = *(const short8*)(Wh + wo);
            short8 wl8 = *(const short8*)(Wl + wo);
            acc[nt] = __builtin_amdgcn_mfma_f32_16x16x32_bf16(wh8, bxh, acc[nt], 0, 0, 0);
            acc[nt] = __builtin_amdgcn_mfma_f32_16x16x32_bf16(wl8, bxh, acc[nt], 0, 0, 0);
            acc[nt] = __builtin_amdgcn_mfma_f32_16x16x32_bf16(wh8, bxl, acc[nt], 0, 0, 0);
        }
    }

    // D layout (verified m89/m91): col=lane&15 -> B col (x row r0+m),
    // row=(lane>>4)*4+reg -> A row (out col o0+nt*16+q*4+reg).
    // => each lane holds 4 consecutive out-cols: one float4 store per tile.
    #pragma unroll
    for (int nt = 0; nt < 2; ++nt) {
        float4 v = make_float4(acc[nt][0], acc[nt][1], acc[nt][2], acc[nt][3]);
        *(float4*)(out + (size_t)(r0 + m) * 256 + o0 + nt * 16 + q * 4) = v;
    }
}

extern "C" void kernel_launch(void* const* d_in, const int* in_sizes, int n_in,
                              void* d_out, int out_size, void* d_ws, size_t ws_size,
                              hipStream_t stream) {
    const float* x = (const float*)d_in[0];   // [4][2048][256] fp32
    // d_in[1] = adj (dead), d_in[3] = a_w (dead)
    const float* W = (const float*)d_in[2];   // [256][256] fp32
    float* out     = (float*)d_out;           // [4][2048][256] fp32

    short* Wh = (short*)d_ws;                 // 65536 bf16 = 128 KB
    short* Wl = Wh + 65536;                   // 128 KB

    split_w<<<64, 256, 0, stream>>>(W, Wh, Wl);
    gat_gemm<<<1024, 256, 0, stream>>>(x, Wh, Wl, out);
}

// Round 3
// 106.251 us; speedup vs baseline: 1.0901x; 1.0901x over previous
//
#include <hip/hip_runtime.h>

// GATLayer reduces to out = x @ W^T:
//   out = einsum('bnjh,bnhd->bnhd', alpha, h); j appears only in alpha and
//   softmax over j sums to 1 (self-edge guarantees a finite row)
//   => out = h = x @ W^T for ANY adj / a_w (both numerically dead).
// B=4, N=2048, IN=256, OUT=256.
//
// Error-compensated bf16 MFMA (Ootomo split), scale-robust ~2^-17 rel err:
//   acc += Wh*Xh + Wl*Xh + Wh*Xl   (A-operand = W, B-operand = X)
//
// Harness floor: ~100us of per-replay re-poison fills dominates dur_us; our
// controllable share is the single kernel below. Hence: ONE dispatch, no
// workspace, minimal in-loop VALU.
//   - 512 blocks x 256 thr; block = 32 rows x 128 cols (2 blocks/CU).
//   - W fragment converted once per (it,nt), reused by 2 row-tiles (6 MFMAs)
//     -> half the conversion VALU of the 16-row version at same MFMA count.
//   - operand swap (A=W, B=X) -> out-cols land in D reg dim -> float4 stores.

typedef __attribute__((ext_vector_type(8))) short short8;
typedef __attribute__((ext_vector_type(4))) float floatx4;
typedef __attribute__((ext_vector_type(4))) int intx4;

__device__ inline int cvtpk_bf16(float a, float b) {
    // dst.lo16 = bf16(a), dst.hi16 = bf16(b), RNE
    int r;
    asm("v_cvt_pk_bf16_f32 %0, %1, %2" : "=v"(r) : "v"(a), "v"(b));
    return r;
}
__device__ inline float lo_bf2f(int p) { return __uint_as_float((unsigned)p << 16); }
__device__ inline float hi_bf2f(int p) { return __uint_as_float((unsigned)p & 0xffff0000u); }

#define LSTR 264  // 256 + 8 shorts: 16B-aligned rows, worst aliasing 2-way (free)

__global__ __launch_bounds__(256) void gat_gemm(const float* __restrict__ X,
                                                const float* __restrict__ W,
                                                float* __restrict__ out) {
    __shared__ short xh[32 * LSTR];   // 16.9 KB
    __shared__ short xl[32 * LSTR];   // 16.9 KB

    const int rb = blockIdx.x >> 1;   // row-tile (0..255)
    const int cb = blockIdx.x & 1;    // col half (0..1)
    const int r0 = rb * 32;
    const int t  = threadIdx.x;

    // Stage 32 rows x 256 f (fp32 -> bf16 hi+lo). 2048 float4 loads, 8/thread.
    const float4* X4 = (const float4*)(X + (size_t)r0 * 256);
    #pragma unroll
    for (int k = 0; k < 8; ++k) {
        int idx = t + 256 * k;          // 0..2047
        int row = idx >> 6;             // 64 float4 per row
        int c4  = idx & 63;
        float4 v = X4[idx];
        int h0 = cvtpk_bf16(v.x, v.y);
        int h1 = cvtpk_bf16(v.z, v.w);
        int l0 = cvtpk_bf16(v.x - lo_bf2f(h0), v.y - hi_bf2f(h0));
        int l1 = cvtpk_bf16(v.z - lo_bf2f(h1), v.w - hi_bf2f(h1));
        *(int2*)&xh[row * LSTR + c4 * 4] = make_int2(h0, h1);
        *(int2*)&xl[row * LSTR + c4 * 4] = make_int2(l0, l1);
    }
    __syncthreads();

    const int lane = t & 63;
    const int wave = t >> 6;            // 4 waves; wave w -> 32-col slice
    const int q    = lane >> 4;         // k-group (0..3)
    const int m    = lane & 15;         // A-row (W row) / B-col (x row) index
    const int o0   = cb * 128 + wave * 32;

    floatx4 acc[2][2] = {};             // [row-tile][col-tile]

    #pragma unroll
    for (int it = 0; it < 8; ++it) {
        const int f0 = it * 32 + q * 8;
        // B operand (x): lane m holds x row (r0 + rt*16 + m), k = f0..f0+7
        short8 bxh0 = *(const short8*)&xh[m * LSTR + f0];
        short8 bxl0 = *(const short8*)&xl[m * LSTR + f0];
        short8 bxh1 = *(const short8*)&xh[(16 + m) * LSTR + f0];
        short8 bxl1 = *(const short8*)&xl[(16 + m) * LSTR + f0];
        #pragma unroll
        for (int nt = 0; nt < 2; ++nt) {
            // A operand (W): lane m holds W row o0+nt*16+m, k = f0..f0+7
            const float* wp = W + (size_t)(o0 + nt * 16 + m) * 256 + f0;
            float4 w0 = *(const float4*)wp;
            float4 w1 = *(const float4*)(wp + 4);
            int bh0 = cvtpk_bf16(w0.x, w0.y);
            int bh1 = cvtpk_bf16(w0.z, w0.w);
            int bh2 = cvtpk_bf16(w1.x, w1.y);
            int bh3 = cvtpk_bf16(w1.z, w1.w);
            int bl0 = cvtpk_bf16(w0.x - lo_bf2f(bh0), w0.y - hi_bf2f(bh0));
            int bl1 = cvtpk_bf16(w0.z - lo_bf2f(bh1), w0.w - hi_bf2f(bh1));
            int bl2 = cvtpk_bf16(w1.x - lo_bf2f(bh2), w1.y - hi_bf2f(bh2));
            int bl3 = cvtpk_bf16(w1.z - lo_bf2f(bh3), w1.w - hi_bf2f(bh3));
            short8 wh8 = __builtin_bit_cast(short8, (intx4){bh0, bh1, bh2, bh3});
            short8 wl8 = __builtin_bit_cast(short8, (intx4){bl0, bl1, bl2, bl3});
            // 6 MFMAs per converted W fragment (2 row-tiles x Ootomo-3)
            acc[0][nt] = __builtin_amdgcn_mfma_f32_16x16x32_bf16(wh8, bxh0, acc[0][nt], 0, 0, 0);
            acc[0][nt] = __builtin_amdgcn_mfma_f32_16x16x32_bf16(wl8, bxh0, acc[0][nt], 0, 0, 0);
            acc[0][nt] = __builtin_amdgcn_mfma_f32_16x16x32_bf16(wh8, bxl0, acc[0][nt], 0, 0, 0);
            acc[1][nt] = __builtin_amdgcn_mfma_f32_16x16x32_bf16(wh8, bxh1, acc[1][nt], 0, 0, 0);
            acc[1][nt] = __builtin_amdgcn_mfma_f32_16x16x32_bf16(wl8, bxh1, acc[1][nt], 0, 0, 0);
            acc[1][nt] = __builtin_amdgcn_mfma_f32_16x16x32_bf16(wh8, bxl1, acc[1][nt], 0, 0, 0);
        }
    }

    // D layout (verified m89/m91, operand-swapped): col=lane&15 -> x row
    // (r0 + rt*16 + m); row=(lane>>4)*4+reg -> out col (o0+nt*16+q*4+reg).
    // => each lane holds 4 consecutive out-cols: one float4 store per tile.
    #pragma unroll
    for (int rt = 0; rt < 2; ++rt) {
        #pragma unroll
        for (int nt = 0; nt < 2; ++nt) {
            float4 v = make_float4(acc[rt][nt][0], acc[rt][nt][1],
                                   acc[rt][nt][2], acc[rt][nt][3]);
            *(float4*)(out + (size_t)(r0 + rt * 16 + m) * 256 + o0 + nt * 16 + q * 4) = v;
        }
    }
}

extern "C" void kernel_launch(void* const* d_in, const int* in_sizes, int n_in,
                              void* d_out, int out_size, void* d_ws, size_t ws_size,
                              hipStream_t stream) {
    const float* x = (const float*)d_in[0];   // [4][2048][256] fp32
    // d_in[1] = adj (dead), d_in[3] = a_w (dead)
    const float* W = (const float*)d_in[2];   // [256][256] fp32
    float* out     = (float*)d_out;           // [4][2048][256] fp32

    gat_gemm<<<512, 256, 0, stream>>>(x, W, out);
}